// Round 3
// baseline (191.718 us; speedup 1.0000x reference)
//
#include <hip/hip_runtime.h>
#include <hip/hip_cooperative_groups.h>

namespace cg = cooperative_groups;

// GNNEmbeds: 3-layer NNConv, scalar edge features.
// W(e) = attr_e*A + B  =>  msg_e = attr_e*(h[src]@A) + (h[src]@B)
// One cooperative kernel; phases separated by grid.sync():
//   P0: AGG1 = x@root1+bias1
//   P1: AGG1[dst] += attr*(x[src]@A1) + x[src]@B1       (global atomics, on-the-fly)
//   P2: h1=relu(AGG1); U2=h1@A2, V2=h1@B2, AGG2=h1@root2+bias2
//   P3: AGG2[dst] += attr*U2[src]+V2[src]
//   P4: h2=relu(AGG2); U3,V3, out=h2@root3+bias3
//   P5: out[dst] += attr*U3[src]+V3[src]

#define HD   128
#define TRR  16     // rows per GEMM tile -> 64 tiles x 3 mats = 192 jobs
#define NBLK 192
#define NTHR 256

struct Params {
    const float* x; const int* ei; const float* attr;
    const float* lw1; const float* lb1; const float* root1; const float* bias1;
    const float* lw2; const float* lb2; const float* root2; const float* bias2;
    const float* lw3; const float* lb3; const float* root3; const float* bias3;
    float* AGG1; float* U2; float* V2; float* AGG2; float* U3; float* V3;
    float* out; int N; int E;
};

__device__ __forceinline__ void node_linear_l1(const Params& p, int gtid, int gsz) {
    const int total = p.N * HD;
    for (int i = gtid; i < total; i += gsz) {
        const int n = i >> 7, c = i & 127;
        const float x0 = p.x[n * 2 + 0], x1 = p.x[n * 2 + 1];
        p.AGG1[i] = fmaf(x0, p.root1[c], fmaf(x1, p.root1[HD + c], p.bias1[c]));
    }
}

__device__ __forceinline__ void scatter_l1(const Params& p, int gtid, int gsz) {
    const int total = p.E * 32;
    for (int i = gtid; i < total; i += gsz) {
        const int e = i >> 5, c = (i & 31) << 2;
        const int s = p.ei[e], d = p.ei[p.E + e];
        const float a = p.attr[e];
        const float x0 = p.x[s * 2 + 0], x1 = p.x[s * 2 + 1];
        const float4 a0 = *(const float4*)(p.lw1 + c);
        const float4 a1 = *(const float4*)(p.lw1 + HD + c);
        const float4 b0 = *(const float4*)(p.lb1 + c);
        const float4 b1 = *(const float4*)(p.lb1 + HD + c);
        float* q = p.AGG1 + (size_t)d * HD + c;
        atomicAdd(q + 0, fmaf(a, fmaf(x0, a0.x, x1 * a1.x), fmaf(x0, b0.x, x1 * b1.x)));
        atomicAdd(q + 1, fmaf(a, fmaf(x0, a0.y, x1 * a1.y), fmaf(x0, b0.y, x1 * b1.y)));
        atomicAdd(q + 2, fmaf(a, fmaf(x0, a0.z, x1 * a1.z), fmaf(x0, b0.z, x1 * b1.z)));
        atomicAdd(q + 3, fmaf(a, fmaf(x0, a0.w, x1 * a1.w), fmaf(x0, b0.w, x1 * b1.w)));
    }
}

__device__ __forceinline__ void scatter_uv(const float* __restrict__ U,
                                           const float* __restrict__ V,
                                           float* __restrict__ AGG,
                                           const Params& p, int gtid, int gsz) {
    const int total = p.E * 32;
    for (int i = gtid; i < total; i += gsz) {
        const int e = i >> 5, c = (i & 31) << 2;
        const int s = p.ei[e], d = p.ei[p.E + e];
        const float a = p.attr[e];
        const float4 u = *(const float4*)(U + (size_t)s * HD + c);
        const float4 v = *(const float4*)(V + (size_t)s * HD + c);
        float* q = AGG + (size_t)d * HD + c;
        atomicAdd(q + 0, fmaf(a, u.x, v.x));
        atomicAdd(q + 1, fmaf(a, u.y, v.y));
        atomicAdd(q + 2, fmaf(a, u.z, v.z));
        atomicAdd(q + 3, fmaf(a, u.w, v.w));
    }
}

// h_relu(tile) @ {A,B,root}; R gets +bias. 192 jobs, one per block.
__device__ __forceinline__ void gemm_phase(
    const float* __restrict__ hin,
    const float* __restrict__ Wa, const float* __restrict__ Wb,
    const float* __restrict__ Wr, const float* __restrict__ bias,
    float* __restrict__ U, float* __restrict__ V, float* __restrict__ R,
    float (*hs)[HD], int N, int t)
{
    const int ntiles = N / TRR;
    const int njobs = ntiles * 3;
    for (int job = blockIdx.x; job < njobs; job += gridDim.x) {
        const int tile = job % ntiles;
        const int y = job / ntiles;
        const int n0 = tile * TRR;

        const float4* src4 = (const float4*)(hin + (size_t)n0 * HD);
        float4* dst4 = (float4*)&hs[0][0];
        for (int i = t; i < TRR * HD / 4; i += NTHR) {
            float4 v = src4[i];
            v.x = fmaxf(v.x, 0.f); v.y = fmaxf(v.y, 0.f);
            v.z = fmaxf(v.z, 0.f); v.w = fmaxf(v.w, 0.f);
            dst4[i] = v;
        }
        __syncthreads();

        const float* W = (y == 0) ? Wa : (y == 1) ? Wb : Wr;
        float* O       = (y == 0) ? U  : (y == 1) ? V  : R;

        const int colg = (t & 31) << 2;   // 4 contiguous cols
        const int rowg = (t >> 5) << 1;   // 2 rows x 8 groups = 16 rows

        float acc[2][4];
#pragma unroll
        for (int r = 0; r < 2; ++r)
#pragma unroll
            for (int c = 0; c < 4; ++c) acc[r][c] = 0.f;

#pragma unroll 8
        for (int k = 0; k < HD; ++k) {
            const float4 w = *(const float4*)(W + (size_t)k * HD + colg);
            const float h0 = hs[rowg + 0][k];
            const float h1 = hs[rowg + 1][k];
            acc[0][0] = fmaf(h0, w.x, acc[0][0]); acc[0][1] = fmaf(h0, w.y, acc[0][1]);
            acc[0][2] = fmaf(h0, w.z, acc[0][2]); acc[0][3] = fmaf(h0, w.w, acc[0][3]);
            acc[1][0] = fmaf(h1, w.x, acc[1][0]); acc[1][1] = fmaf(h1, w.y, acc[1][1]);
            acc[1][2] = fmaf(h1, w.z, acc[1][2]); acc[1][3] = fmaf(h1, w.w, acc[1][3]);
        }

        float4 b = make_float4(0.f, 0.f, 0.f, 0.f);
        if (y == 2) b = *(const float4*)(bias + colg);
#pragma unroll
        for (int r = 0; r < 2; ++r) {
            float4 o;
            o.x = acc[r][0] + b.x; o.y = acc[r][1] + b.y;
            o.z = acc[r][2] + b.z; o.w = acc[r][3] + b.w;
            *(float4*)(O + (size_t)(n0 + rowg + r) * HD + colg) = o;
        }
        __syncthreads();
    }
}

__global__ __launch_bounds__(NTHR) void fused(Params p) {
    cg::grid_group grid = cg::this_grid();
    const int t = threadIdx.x;
    const int gtid = blockIdx.x * NTHR + t;
    const int gsz = gridDim.x * NTHR;
    __shared__ float hs[TRR][HD];

    node_linear_l1(p, gtid, gsz);
    grid.sync();
    scatter_l1(p, gtid, gsz);
    grid.sync();
    gemm_phase(p.AGG1, p.lw2, p.lb2, p.root2, p.bias2, p.U2, p.V2, p.AGG2, hs, p.N, t);
    grid.sync();
    scatter_uv(p.U2, p.V2, p.AGG2, p, gtid, gsz);
    grid.sync();
    gemm_phase(p.AGG2, p.lw3, p.lb3, p.root3, p.bias3, p.U3, p.V3, p.out, hs, p.N, t);
    grid.sync();
    scatter_uv(p.U3, p.V3, p.out, p, gtid, gsz);
}

extern "C" void kernel_launch(void* const* d_in, const int* in_sizes, int n_in,
                              void* d_out, int out_size, void* d_ws, size_t ws_size,
                              hipStream_t stream) {
    Params p;
    p.x     = (const float*)d_in[0];
    p.ei    = (const int*)  d_in[1];
    p.attr  = (const float*)d_in[2];
    p.lw1   = (const float*)d_in[3];
    p.lb1   = (const float*)d_in[4];
    p.root1 = (const float*)d_in[5];
    p.bias1 = (const float*)d_in[6];
    p.lw2   = (const float*)d_in[7];
    p.lb2   = (const float*)d_in[8];
    p.root2 = (const float*)d_in[9];
    p.bias2 = (const float*)d_in[10];
    p.lw3   = (const float*)d_in[11];
    p.lb3   = (const float*)d_in[12];
    p.root3 = (const float*)d_in[13];
    p.bias3 = (const float*)d_in[14];

    p.N = in_sizes[0] / 2;   // x: [N,2]
    p.E = in_sizes[1] / 2;   // edge_index: [2,E]

    float* ws = (float*)d_ws;
    p.AGG1 = ws + 0 * (size_t)p.N * HD;
    p.U2   = ws + 1 * (size_t)p.N * HD;
    p.V2   = ws + 2 * (size_t)p.N * HD;
    p.AGG2 = ws + 3 * (size_t)p.N * HD;
    p.U3   = ws + 4 * (size_t)p.N * HD;
    p.V3   = ws + 5 * (size_t)p.N * HD;
    p.out  = (float*)d_out;

    void* args[] = { &p };
    hipLaunchCooperativeKernel((const void*)fused, dim3(NBLK), dim3(NTHR),
                               args, 0, stream);
}

// Round 4
// 133.605 us; speedup vs baseline: 1.4350x; 1.4350x over previous
//
#include <hip/hip_runtime.h>

// GNNEmbeds: 3-layer NNConv, scalar edge features.
// W(e) = attr_e*A + B  =>  msg_e = attr_e*(h[src]@A) + (h[src]@B)
// Per layer: U = h@A, V = h@B, R = h@root + bias; h_next_tile = relu(R_tile + gather).
// Gather-into-consumer: each block owns a TR-row dst tile, scans the dst array
// once (int4, L2-broadcast), builds an LDS edge list, accumulates messages with
// LDS atomics, then runs one of the three next-layer GEMMs (blockIdx.y).
// 3 dispatches total, no global atomics, no grid sync.

#define HD   128
#define TR   16     // dst rows per tile (N=1024 -> 64 tiles)
#define CAP  512    // LDS edge-list capacity (avg 128/tile for E=8192; 4x headroom)
#define NTHR 256

// ---- scan dst array, append matching edges to LDS list ----
__device__ __forceinline__ void scan_edges(
    const int* __restrict__ ei, const float* __restrict__ attr, int E, int n0,
    int* __restrict__ lrow, int* __restrict__ lsrc, float* __restrict__ lattr,
    int* __restrict__ lcnt, int t)
{
    if (t == 0) *lcnt = 0;
    __syncthreads();   // also orders prior hs-init writes before gather
    const int4* dst4 = (const int4*)(ei + E);
    const int nq = E >> 2;
    for (int i = t; i < nq; i += NTHR) {
        const int4 d = dst4[i];
        const int e0 = i << 2;
        unsigned r;
        r = (unsigned)(d.x - n0);
        if (r < TR) { int k = atomicAdd(lcnt, 1); if (k < CAP) { lrow[k] = r; lsrc[k] = ei[e0 + 0]; lattr[k] = attr[e0 + 0]; } }
        r = (unsigned)(d.y - n0);
        if (r < TR) { int k = atomicAdd(lcnt, 1); if (k < CAP) { lrow[k] = r; lsrc[k] = ei[e0 + 1]; lattr[k] = attr[e0 + 1]; } }
        r = (unsigned)(d.z - n0);
        if (r < TR) { int k = atomicAdd(lcnt, 1); if (k < CAP) { lrow[k] = r; lsrc[k] = ei[e0 + 2]; lattr[k] = attr[e0 + 2]; } }
        r = (unsigned)(d.w - n0);
        if (r < TR) { int k = atomicAdd(lcnt, 1); if (k < CAP) { lrow[k] = r; lsrc[k] = ei[e0 + 3]; lattr[k] = attr[e0 + 3]; } }
    }
    for (int e = (E & ~3) + t; e < E; e += NTHR) {   // tail (E%4), usually empty
        const unsigned r = (unsigned)(ei[E + e] - n0);
        if (r < TR) { int k = atomicAdd(lcnt, 1); if (k < CAP) { lrow[k] = r; lsrc[k] = ei[e]; lattr[k] = attr[e]; } }
    }
    __syncthreads();
}

// ---- GEMM: out{U,V,R} tile = hs @ {A,B,root} (+bias for R) ----
__device__ __forceinline__ void gemm_from_lds(
    const float hs[TR][HD], int n0, int t, int y,
    const float* __restrict__ Wa, const float* __restrict__ Wb,
    const float* __restrict__ Wr, const float* __restrict__ bias,
    float* __restrict__ U, float* __restrict__ V, float* __restrict__ R)
{
    const float* W = (y == 0) ? Wa : (y == 1) ? Wb : Wr;
    float* O       = (y == 0) ? U  : (y == 1) ? V  : R;

    const int colg = (t & 31) << 2;   // 4 contiguous cols
    const int rowg = (t >> 5) << 1;   // 2 rows x 8 groups = 16 rows

    float acc[2][4];
#pragma unroll
    for (int r = 0; r < 2; ++r)
#pragma unroll
        for (int c = 0; c < 4; ++c) acc[r][c] = 0.f;

#pragma unroll 8
    for (int k = 0; k < HD; ++k) {
        const float4 w = *(const float4*)(W + (size_t)k * HD + colg);
        const float h0 = hs[rowg + 0][k];
        const float h1 = hs[rowg + 1][k];
        acc[0][0] = fmaf(h0, w.x, acc[0][0]); acc[0][1] = fmaf(h0, w.y, acc[0][1]);
        acc[0][2] = fmaf(h0, w.z, acc[0][2]); acc[0][3] = fmaf(h0, w.w, acc[0][3]);
        acc[1][0] = fmaf(h1, w.x, acc[1][0]); acc[1][1] = fmaf(h1, w.y, acc[1][1]);
        acc[1][2] = fmaf(h1, w.z, acc[1][2]); acc[1][3] = fmaf(h1, w.w, acc[1][3]);
    }

    float4 b = make_float4(0.f, 0.f, 0.f, 0.f);
    if (y == 2) b = *(const float4*)(bias + colg);
#pragma unroll
    for (int r = 0; r < 2; ++r) {
        float4 o;
        o.x = acc[r][0] + b.x; o.y = acc[r][1] + b.y;
        o.z = acc[r][2] + b.z; o.w = acc[r][3] + b.w;
        *(float4*)(O + (size_t)(n0 + rowg + r) * HD + colg) = o;
    }
}

// ---- G2: L1 gather (msgs on-the-fly from x) + L2 GEMMs ----
__global__ __launch_bounds__(NTHR) void g2(
    const float* __restrict__ x, const int* __restrict__ ei,
    const float* __restrict__ attr,
    const float* __restrict__ lw1, const float* __restrict__ lb1,
    const float* __restrict__ root1, const float* __restrict__ bias1,
    const float* __restrict__ lw2, const float* __restrict__ lb2,
    const float* __restrict__ root2, const float* __restrict__ bias2,
    float* __restrict__ U2, float* __restrict__ V2, float* __restrict__ R2,
    int E)
{
    __shared__ float hs[TR][HD];
    __shared__ int lrow[CAP]; __shared__ int lsrc[CAP]; __shared__ float lattr[CAP];
    __shared__ int lcnt;
    const int t = threadIdx.x;
    const int n0 = blockIdx.x * TR;

    // hs = x@root1 + bias1 (root-term of layer 1)
    for (int i = t; i < TR * HD; i += NTHR) {
        const int r = i >> 7, c = i & 127;
        const float x0 = x[(n0 + r) * 2 + 0], x1 = x[(n0 + r) * 2 + 1];
        hs[r][c] = fmaf(x0, root1[c], fmaf(x1, root1[HD + c], bias1[c]));
    }

    scan_edges(ei, attr, E, n0, lrow, lsrc, lattr, &lcnt, t);
    const int cnt = (lcnt < CAP) ? lcnt : CAP;

    // gather: hs[r][c] += a*(x@A1)[c] + (x@B1)[c]
    const int c = t & 127, half = t >> 7;
    const float a1c0 = lw1[c], a1c1 = lw1[HD + c];
    const float b1c0 = lb1[c], b1c1 = lb1[HD + c];
    for (int i = half; i < cnt; i += 2) {
        const int r = lrow[i], s = lsrc[i];
        const float a = lattr[i];
        const float x0 = x[s * 2 + 0], x1 = x[s * 2 + 1];
        const float m = fmaf(a, fmaf(x0, a1c0, x1 * a1c1),
                                fmaf(x0, b1c0, x1 * b1c1));
        atomicAdd(&hs[r][c], m);
    }
    __syncthreads();

    for (int i = t; i < TR * HD; i += NTHR)
        (&hs[0][0])[i] = fmaxf((&hs[0][0])[i], 0.f);
    __syncthreads();

    gemm_from_lds(hs, n0, t, blockIdx.y, lw2, lb2, root2, bias2, U2, V2, R2);
}

// ---- G3: L2 gather (from U2,V2; init R2) + L3 GEMMs ----
__global__ __launch_bounds__(NTHR) void g3(
    const int* __restrict__ ei, const float* __restrict__ attr,
    const float* __restrict__ U2, const float* __restrict__ V2,
    const float* __restrict__ R2,
    const float* __restrict__ lw3, const float* __restrict__ lb3,
    const float* __restrict__ root3, const float* __restrict__ bias3,
    float* __restrict__ U3, float* __restrict__ V3, float* __restrict__ R3,
    int E)
{
    __shared__ float hs[TR][HD];
    __shared__ int lrow[CAP]; __shared__ int lsrc[CAP]; __shared__ float lattr[CAP];
    __shared__ int lcnt;
    const int t = threadIdx.x;
    const int n0 = blockIdx.x * TR;

    for (int i = t; i < TR * HD / 4; i += NTHR)
        ((float4*)&hs[0][0])[i] = ((const float4*)(R2 + (size_t)n0 * HD))[i];

    scan_edges(ei, attr, E, n0, lrow, lsrc, lattr, &lcnt, t);
    const int cnt = (lcnt < CAP) ? lcnt : CAP;

    const int c = t & 127, half = t >> 7;
    for (int i = half; i < cnt; i += 2) {
        const int r = lrow[i], s = lsrc[i];
        const float a = lattr[i];
        const float u = U2[(size_t)s * HD + c];
        const float v = V2[(size_t)s * HD + c];
        atomicAdd(&hs[r][c], fmaf(a, u, v));
    }
    __syncthreads();

    for (int i = t; i < TR * HD; i += NTHR)
        (&hs[0][0])[i] = fmaxf((&hs[0][0])[i], 0.f);
    __syncthreads();

    gemm_from_lds(hs, n0, t, blockIdx.y, lw3, lb3, root3, bias3, U3, V3, R3);
}

// ---- G4: L3 gather -> out (no relu, plain stores) ----
__global__ __launch_bounds__(NTHR) void g4(
    const int* __restrict__ ei, const float* __restrict__ attr,
    const float* __restrict__ U3, const float* __restrict__ V3,
    const float* __restrict__ R3, float* __restrict__ out, int E)
{
    __shared__ float hs[TR][HD];
    __shared__ int lrow[CAP]; __shared__ int lsrc[CAP]; __shared__ float lattr[CAP];
    __shared__ int lcnt;
    const int t = threadIdx.x;
    const int n0 = blockIdx.x * TR;

    for (int i = t; i < TR * HD / 4; i += NTHR)
        ((float4*)&hs[0][0])[i] = ((const float4*)(R3 + (size_t)n0 * HD))[i];

    scan_edges(ei, attr, E, n0, lrow, lsrc, lattr, &lcnt, t);
    const int cnt = (lcnt < CAP) ? lcnt : CAP;

    const int c = t & 127, half = t >> 7;
    for (int i = half; i < cnt; i += 2) {
        const int r = lrow[i], s = lsrc[i];
        const float a = lattr[i];
        const float u = U3[(size_t)s * HD + c];
        const float v = V3[(size_t)s * HD + c];
        atomicAdd(&hs[r][c], fmaf(a, u, v));
    }
    __syncthreads();

    for (int i = t; i < TR * HD / 4; i += NTHR)
        ((float4*)(out + (size_t)n0 * HD))[i] = ((const float4*)&hs[0][0])[i];
}

extern "C" void kernel_launch(void* const* d_in, const int* in_sizes, int n_in,
                              void* d_out, int out_size, void* d_ws, size_t ws_size,
                              hipStream_t stream) {
    const float* x     = (const float*)d_in[0];
    const int*   ei    = (const int*)  d_in[1];
    const float* attr  = (const float*)d_in[2];
    const float* lw1   = (const float*)d_in[3];
    const float* lb1   = (const float*)d_in[4];
    const float* root1 = (const float*)d_in[5];
    const float* bias1 = (const float*)d_in[6];
    const float* lw2   = (const float*)d_in[7];
    const float* lb2   = (const float*)d_in[8];
    const float* root2 = (const float*)d_in[9];
    const float* bias2 = (const float*)d_in[10];
    const float* lw3   = (const float*)d_in[11];
    const float* lb3   = (const float*)d_in[12];
    const float* root3 = (const float*)d_in[13];
    const float* bias3 = (const float*)d_in[14];

    const int N = in_sizes[0] / 2;   // x: [N,2]
    const int E = in_sizes[1] / 2;   // edge_index: [2,E]

    float* out = (float*)d_out;
    float* ws  = (float*)d_ws;
    float* U2 = ws + 0 * (size_t)N * HD;
    float* V2 = ws + 1 * (size_t)N * HD;
    float* R2 = ws + 2 * (size_t)N * HD;
    float* U3 = ws + 3 * (size_t)N * HD;
    float* V3 = ws + 4 * (size_t)N * HD;
    float* R3 = ws + 5 * (size_t)N * HD;

    const int ntiles = N / TR;
    g2<<<dim3(ntiles, 3), NTHR, 0, stream>>>(x, ei, attr, lw1, lb1, root1, bias1,
                                             lw2, lb2, root2, bias2, U2, V2, R2, E);
    g3<<<dim3(ntiles, 3), NTHR, 0, stream>>>(ei, attr, U2, V2, R2,
                                             lw3, lb3, root3, bias3, U3, V3, R3, E);
    g4<<<dim3(ntiles), NTHR, 0, stream>>>(ei, attr, U3, V3, R3, out, E);
}

// Round 5
// 91.943 us; speedup vs baseline: 2.0852x; 1.4531x over previous
//
#include <hip/hip_runtime.h>

// GNNEmbeds: 3-layer NNConv, scalar edge features.
// W(e) = attr_e*A + B  =>  msg_e = attr_e*(h[src]@A) + (h[src]@B)
// Per layer: U = h@A, V = h@B, R = h@root + bias; h_next = relu(R + gather(msgs)).
// 3 dispatches, gather-into-consumer, no global atomics, no grid sync.
// Round-5 fixes: TR=8 (128 blocks), branch-free float4 gather (8 edges in
// flight, unroll 4), int4 scan with match-only src/attr loads, all three
// GEMMs fused into one k-loop per block.

#define HD    128
#define TR    8        // dst rows per tile -> N=1024 gives 128 blocks
#define CAP   256      // LDS edge-list capacity (mean 64/tile; 24-sigma headroom)
#define NTHR  256
#define SCRATCH TR     // dummy row for pad edges

struct Tile {
    float hs[TR + 1][HD];     // +1 scratch row for pad edges
    int   lrow[CAP + 8];
    int   lsrc[CAP + 8];
    float lattr[CAP + 8];
    int   lcnt;
};

// Scan dst array (int4), append matching edges to LDS list, pad to mult of 8.
// Returns padded count. First barrier also orders prior hs-init writes.
__device__ __forceinline__ int scan_edges(const int* __restrict__ ei,
                                          const float* __restrict__ attr,
                                          int E, int n0, Tile& g, int t)
{
    if (t == 0) g.lcnt = 0;
    __syncthreads();
    const int nq = E >> 2;
    const int4*   src4 = (const int4*)ei;
    const int4*   dst4 = (const int4*)(ei + E);
    const float4* at4  = (const float4*)attr;
    for (int i = t; i < nq; i += NTHR) {
        const int4 d = dst4[i];
        const unsigned r0 = (unsigned)(d.x - n0);
        const unsigned r1 = (unsigned)(d.y - n0);
        const unsigned r2 = (unsigned)(d.z - n0);
        const unsigned r3 = (unsigned)(d.w - n0);
        if ((r0 < TR) || (r1 < TR) || (r2 < TR) || (r3 < TR)) {
            const int4   s = src4[i];
            const float4 a = at4[i];
            if (r0 < TR) { int k = atomicAdd(&g.lcnt, 1); if (k < CAP) { g.lrow[k] = r0; g.lsrc[k] = s.x; g.lattr[k] = a.x; } }
            if (r1 < TR) { int k = atomicAdd(&g.lcnt, 1); if (k < CAP) { g.lrow[k] = r1; g.lsrc[k] = s.y; g.lattr[k] = a.y; } }
            if (r2 < TR) { int k = atomicAdd(&g.lcnt, 1); if (k < CAP) { g.lrow[k] = r2; g.lsrc[k] = s.z; g.lattr[k] = a.z; } }
            if (r3 < TR) { int k = atomicAdd(&g.lcnt, 1); if (k < CAP) { g.lrow[k] = r3; g.lsrc[k] = s.w; g.lattr[k] = a.w; } }
        }
    }
    for (int e = (E & ~3) + t; e < E; e += NTHR) {   // E%4 tail (empty for E=8192)
        const unsigned r = (unsigned)(ei[E + e] - n0);
        if (r < TR) { int k = atomicAdd(&g.lcnt, 1); if (k < CAP) { g.lrow[k] = r; g.lsrc[k] = ei[e]; g.lattr[k] = attr[e]; } }
    }
    __syncthreads();
    int cnt = g.lcnt; if (cnt > CAP) cnt = CAP;
    const int pad = (cnt + 7) & ~7;
    if (t < pad - cnt) {           // dummy edges land in scratch row
        const int k = cnt + t;
        g.lrow[k] = SCRATCH; g.lsrc[k] = 0; g.lattr[k] = 0.f;
    }
    __syncthreads();
    return pad;
}

// hs[r] += a*U[s] + V[s] for each listed edge. 8 edges in flight, float4 lanes.
__device__ __forceinline__ void gather_uv(const float* __restrict__ U,
                                          const float* __restrict__ V,
                                          Tile& g, int pad, int t)
{
    const int el = t >> 5;          // edge slot 0..7
    const int c4 = (t & 31) << 2;   // 4 contiguous cols
#pragma unroll 4
    for (int base = 0; base < pad; base += 8) {
        const int   i = base + el;
        const int   r = g.lrow[i];
        const int   s = g.lsrc[i];
        const float a = g.lattr[i];
        const float4 u = *(const float4*)(U + (size_t)s * HD + c4);
        const float4 v = *(const float4*)(V + (size_t)s * HD + c4);
        atomicAdd(&g.hs[r][c4 + 0], fmaf(a, u.x, v.x));
        atomicAdd(&g.hs[r][c4 + 1], fmaf(a, u.y, v.y));
        atomicAdd(&g.hs[r][c4 + 2], fmaf(a, u.z, v.z));
        atomicAdd(&g.hs[r][c4 + 3], fmaf(a, u.w, v.w));
    }
    __syncthreads();
}

__device__ __forceinline__ void relu_hs(Tile& g, int t) {
    for (int i = t; i < TR * HD; i += NTHR) {
        float* p = &g.hs[0][0] + i;      // rows 0..TR-1 are contiguous
        *p = fmaxf(*p, 0.f);
    }
    __syncthreads();
}

// {U,V,R}[tile] = hs @ {Wa,Wb,Wr}; R += bias. One row per 32-thread group.
__device__ __forceinline__ void gemm3(const Tile& g, int n0, int t,
    const float* __restrict__ Wa, const float* __restrict__ Wb,
    const float* __restrict__ Wr, const float* __restrict__ bias,
    float* __restrict__ U, float* __restrict__ V, float* __restrict__ R)
{
    const int colg = (t & 31) << 2;
    const int row  = t >> 5;
    float a0=0,a1=0,a2=0,a3=0, b0=0,b1=0,b2=0,b3=0, c0=0,c1=0,c2=0,c3=0;
#pragma unroll 8
    for (int k = 0; k < HD; ++k) {
        const float h = g.hs[row][k];    // LDS broadcast within group
        const float4 wa = *(const float4*)(Wa + (size_t)k * HD + colg);
        const float4 wb = *(const float4*)(Wb + (size_t)k * HD + colg);
        const float4 wr = *(const float4*)(Wr + (size_t)k * HD + colg);
        a0 = fmaf(h, wa.x, a0); a1 = fmaf(h, wa.y, a1);
        a2 = fmaf(h, wa.z, a2); a3 = fmaf(h, wa.w, a3);
        b0 = fmaf(h, wb.x, b0); b1 = fmaf(h, wb.y, b1);
        b2 = fmaf(h, wb.z, b2); b3 = fmaf(h, wb.w, b3);
        c0 = fmaf(h, wr.x, c0); c1 = fmaf(h, wr.y, c1);
        c2 = fmaf(h, wr.z, c2); c3 = fmaf(h, wr.w, c3);
    }
    const float4 bv = *(const float4*)(bias + colg);
    const size_t o = (size_t)(n0 + row) * HD + colg;
    *(float4*)(U + o) = make_float4(a0, a1, a2, a3);
    *(float4*)(V + o) = make_float4(b0, b1, b2, b3);
    *(float4*)(R + o) = make_float4(c0 + bv.x, c1 + bv.y, c2 + bv.z, c3 + bv.w);
}

// ---- G2: layer-1 gather (msgs on the fly from x, in_c=2) + layer-2 GEMMs ----
__global__ __launch_bounds__(NTHR) void g2k(
    const float* __restrict__ x, const int* __restrict__ ei,
    const float* __restrict__ attr,
    const float* __restrict__ lw1, const float* __restrict__ lb1,
    const float* __restrict__ root1, const float* __restrict__ bias1,
    const float* __restrict__ lw2, const float* __restrict__ lb2,
    const float* __restrict__ root2, const float* __restrict__ bias2,
    float* __restrict__ U2, float* __restrict__ V2, float* __restrict__ R2,
    int E)
{
    __shared__ Tile g;
    const int t = threadIdx.x;
    const int n0 = blockIdx.x * TR;

    // hs = x@root1 + bias1
    for (int i = t; i < TR * HD; i += NTHR) {
        const int r = i >> 7, c = i & 127;
        const float x0 = x[(n0 + r) * 2 + 0], x1 = x[(n0 + r) * 2 + 1];
        g.hs[r][c] = fmaf(x0, root1[c], fmaf(x1, root1[HD + c], bias1[c]));
    }

    const int pad = scan_edges(ei, attr, E, n0, g, t);

    // gather layer-1 messages: msg[c] = a*(x@A1)[c] + (x@B1)[c]
    const int el = t >> 5;
    const int c4 = (t & 31) << 2;
    const float4 A0 = *(const float4*)(lw1 + c4);
    const float4 A1 = *(const float4*)(lw1 + HD + c4);
    const float4 B0 = *(const float4*)(lb1 + c4);
    const float4 B1 = *(const float4*)(lb1 + HD + c4);
#pragma unroll 4
    for (int base = 0; base < pad; base += 8) {
        const int   i = base + el;
        const int   r = g.lrow[i];
        const int   s = g.lsrc[i];
        const float a = g.lattr[i];
        const float2 xv = *(const float2*)(x + (size_t)s * 2);
        atomicAdd(&g.hs[r][c4 + 0], fmaf(a, fmaf(xv.x, A0.x, xv.y * A1.x), fmaf(xv.x, B0.x, xv.y * B1.x)));
        atomicAdd(&g.hs[r][c4 + 1], fmaf(a, fmaf(xv.x, A0.y, xv.y * A1.y), fmaf(xv.x, B0.y, xv.y * B1.y)));
        atomicAdd(&g.hs[r][c4 + 2], fmaf(a, fmaf(xv.x, A0.z, xv.y * A1.z), fmaf(xv.x, B0.z, xv.y * B1.z)));
        atomicAdd(&g.hs[r][c4 + 3], fmaf(a, fmaf(xv.x, A0.w, xv.y * A1.w), fmaf(xv.x, B0.w, xv.y * B1.w)));
    }
    __syncthreads();

    relu_hs(g, t);
    gemm3(g, n0, t, lw2, lb2, root2, bias2, U2, V2, R2);
}

// ---- G3: layer-2 gather + layer-3 GEMMs ----
__global__ __launch_bounds__(NTHR) void g3k(
    const int* __restrict__ ei, const float* __restrict__ attr,
    const float* __restrict__ U2, const float* __restrict__ V2,
    const float* __restrict__ R2,
    const float* __restrict__ lw3, const float* __restrict__ lb3,
    const float* __restrict__ root3, const float* __restrict__ bias3,
    float* __restrict__ U3, float* __restrict__ V3, float* __restrict__ R3,
    int E)
{
    __shared__ Tile g;
    const int t = threadIdx.x;
    const int n0 = blockIdx.x * TR;

    ((float4*)&g.hs[0][0])[t] = ((const float4*)(R2 + (size_t)n0 * HD))[t];

    const int pad = scan_edges(ei, attr, E, n0, g, t);
    gather_uv(U2, V2, g, pad, t);
    relu_hs(g, t);
    gemm3(g, n0, t, lw3, lb3, root3, bias3, U3, V3, R3);
}

// ---- G4: layer-3 gather -> out (no relu, plain float4 stores) ----
__global__ __launch_bounds__(NTHR) void g4k(
    const int* __restrict__ ei, const float* __restrict__ attr,
    const float* __restrict__ U3, const float* __restrict__ V3,
    const float* __restrict__ R3, float* __restrict__ out, int E)
{
    __shared__ Tile g;
    const int t = threadIdx.x;
    const int n0 = blockIdx.x * TR;

    ((float4*)&g.hs[0][0])[t] = ((const float4*)(R3 + (size_t)n0 * HD))[t];

    const int pad = scan_edges(ei, attr, E, n0, g, t);
    gather_uv(U3, V3, g, pad, t);

    ((float4*)(out + (size_t)n0 * HD))[t] = ((const float4*)&g.hs[0][0])[t];
}

extern "C" void kernel_launch(void* const* d_in, const int* in_sizes, int n_in,
                              void* d_out, int out_size, void* d_ws, size_t ws_size,
                              hipStream_t stream) {
    const float* x     = (const float*)d_in[0];
    const int*   ei    = (const int*)  d_in[1];
    const float* attr  = (const float*)d_in[2];
    const float* lw1   = (const float*)d_in[3];
    const float* lb1   = (const float*)d_in[4];
    const float* root1 = (const float*)d_in[5];
    const float* bias1 = (const float*)d_in[6];
    const float* lw2   = (const float*)d_in[7];
    const float* lb2   = (const float*)d_in[8];
    const float* root2 = (const float*)d_in[9];
    const float* bias2 = (const float*)d_in[10];
    const float* lw3   = (const float*)d_in[11];
    const float* lb3   = (const float*)d_in[12];
    const float* root3 = (const float*)d_in[13];
    const float* bias3 = (const float*)d_in[14];

    const int N = in_sizes[0] / 2;   // x: [N,2]
    const int E = in_sizes[1] / 2;   // edge_index: [2,E]

    float* out = (float*)d_out;
    float* ws  = (float*)d_ws;
    float* U2 = ws + 0 * (size_t)N * HD;
    float* V2 = ws + 1 * (size_t)N * HD;
    float* R2 = ws + 2 * (size_t)N * HD;
    float* U3 = ws + 3 * (size_t)N * HD;
    float* V3 = ws + 4 * (size_t)N * HD;
    float* R3 = ws + 5 * (size_t)N * HD;

    const int ntiles = N / TR;   // 128 blocks
    g2k<<<ntiles, NTHR, 0, stream>>>(x, ei, attr, lw1, lb1, root1, bias1,
                                     lw2, lb2, root2, bias2, U2, V2, R2, E);
    g3k<<<ntiles, NTHR, 0, stream>>>(ei, attr, U2, V2, R2,
                                     lw3, lb3, root3, bias3, U3, V3, R3, E);
    g4k<<<ntiles, NTHR, 0, stream>>>(ei, attr, U3, V3, R3, out, E);
}

// Round 6
// 60.523 us; speedup vs baseline: 3.1677x; 1.5191x over previous
//
#include <hip/hip_runtime.h>

// GNNEmbeds: 3-layer NNConv, scalar edge features.
// W(e) = attr_e*A + B  =>  msg_e = attr_e*(h[src]@A) + (h[src]@B)
// Per layer: U = h@A, V = h@B, R = h@root + bias; h_next = relu(R + gather(msgs)).
// 3 dispatches, gather-into-consumer, no global atomics, no grid sync.
// Round-6: latency attack. TR=4 (256 blocks, 1/CU), 512-thread blocks
// (2 waves/SIMD), GEMM k-split 4-way with register-staged weight batches
// (24 independent float4 loads in flight per batch) + LDS partial reduce.

#define HD    128
#define TR    4        // dst rows per tile -> N=1024 gives 256 blocks
#define CAP   192      // LDS edge-list capacity (mean 32/tile; ~28 sigma)
#define NTHR  512
#define KB    8        // k-rows per register-staged weight batch
#define KSPL  4        // k-split ways (32 k each)
#define SCRATCH TR     // dummy row for pad edges

struct Tile {
    float hs[TR + 1][HD];            // gather accumulator (+ scratch row)
    float pbuf[KSPL - 1][3][TR][HD]; // GEMM partials [kq-1][mat][row][col]
    int   lrow[CAP + 16];
    int   lsrc[CAP + 16];
    float lattr[CAP + 16];
    int   lcnt;
};

__device__ __forceinline__ void fma4(float4& a, float s, const float4& w) {
    a.x = fmaf(s, w.x, a.x); a.y = fmaf(s, w.y, a.y);
    a.z = fmaf(s, w.z, a.z); a.w = fmaf(s, w.w, a.w);
}

// Scan dst array (int4), append matching edges to LDS list, pad to mult of 16.
// First barrier also orders prior hs-init writes.
__device__ __forceinline__ int scan_edges(const int* __restrict__ ei,
                                          const float* __restrict__ attr,
                                          int E, int n0, Tile& g, int t)
{
    if (t == 0) g.lcnt = 0;
    __syncthreads();
    const int nq = E >> 2;
    const int4*   src4 = (const int4*)ei;
    const int4*   dst4 = (const int4*)(ei + E);
    const float4* at4  = (const float4*)attr;
#pragma unroll 4
    for (int i = t; i < nq; i += NTHR) {
        const int4 d = dst4[i];
        const unsigned r0 = (unsigned)(d.x - n0);
        const unsigned r1 = (unsigned)(d.y - n0);
        const unsigned r2 = (unsigned)(d.z - n0);
        const unsigned r3 = (unsigned)(d.w - n0);
        if ((r0 < TR) || (r1 < TR) || (r2 < TR) || (r3 < TR)) {
            const int4   s = src4[i];
            const float4 a = at4[i];
            if (r0 < TR) { int k = atomicAdd(&g.lcnt, 1); if (k < CAP) { g.lrow[k] = r0; g.lsrc[k] = s.x; g.lattr[k] = a.x; } }
            if (r1 < TR) { int k = atomicAdd(&g.lcnt, 1); if (k < CAP) { g.lrow[k] = r1; g.lsrc[k] = s.y; g.lattr[k] = a.y; } }
            if (r2 < TR) { int k = atomicAdd(&g.lcnt, 1); if (k < CAP) { g.lrow[k] = r2; g.lsrc[k] = s.z; g.lattr[k] = a.z; } }
            if (r3 < TR) { int k = atomicAdd(&g.lcnt, 1); if (k < CAP) { g.lrow[k] = r3; g.lsrc[k] = s.w; g.lattr[k] = a.w; } }
        }
    }
    for (int e = (E & ~3) + t; e < E; e += NTHR) {   // E%4 tail (empty here)
        const unsigned r = (unsigned)(ei[E + e] - n0);
        if (r < TR) { int k = atomicAdd(&g.lcnt, 1); if (k < CAP) { g.lrow[k] = r; g.lsrc[k] = ei[e]; g.lattr[k] = attr[e]; } }
    }
    __syncthreads();
    int cnt = g.lcnt; if (cnt > CAP) cnt = CAP;
    const int pad = (cnt + 15) & ~15;
    if (t < pad - cnt) {
        const int k = cnt + t;
        g.lrow[k] = SCRATCH; g.lsrc[k] = 0; g.lattr[k] = 0.f;
    }
    __syncthreads();
    return pad;
}

// hs[r] += a*U[s] + V[s]; 16 edges in flight x float4 lanes.
__device__ __forceinline__ void gather_uv(const float* __restrict__ U,
                                          const float* __restrict__ V,
                                          Tile& g, int pad, int t)
{
    const int el = t >> 5;          // edge slot 0..15
    const int c4 = (t & 31) << 2;   // 4 contiguous cols
#pragma unroll 2
    for (int base = 0; base < pad; base += 16) {
        const int   i = base + el;
        const int   r = g.lrow[i];
        const int   s = g.lsrc[i];
        const float a = g.lattr[i];
        const float4 u = *(const float4*)(U + (size_t)s * HD + c4);
        const float4 v = *(const float4*)(V + (size_t)s * HD + c4);
        atomicAdd(&g.hs[r][c4 + 0], fmaf(a, u.x, v.x));
        atomicAdd(&g.hs[r][c4 + 1], fmaf(a, u.y, v.y));
        atomicAdd(&g.hs[r][c4 + 2], fmaf(a, u.z, v.z));
        atomicAdd(&g.hs[r][c4 + 3], fmaf(a, u.w, v.w));
    }
    __syncthreads();
}

__device__ __forceinline__ void relu_hs(Tile& g, int t) {
    for (int i = t; i < TR * HD; i += NTHR) {
        float* p = &g.hs[0][0] + i;
        *p = fmaxf(*p, 0.f);
    }
    __syncthreads();
}

// {U,V,R}[tile] = hs @ {Wa,Wb,Wr}; R += bias.
// 16 groups of 32 threads: group = (kq, row); kq in 0..3 covers 32 k each.
// Register-staged weight batches: KB=8 k-rows x 3 mats = 24 float4 in flight.
__device__ __forceinline__ void gemm3(Tile& g, int n0, int t,
    const float* __restrict__ Wa, const float* __restrict__ Wb,
    const float* __restrict__ Wr, const float* __restrict__ bias,
    float* __restrict__ U, float* __restrict__ V, float* __restrict__ R)
{
    const int colg = (t & 31) << 2;
    const int grp  = t >> 5;         // 0..15
    const int row  = grp & (TR - 1);
    const int kq   = grp >> 2;       // 0..3
    const int k0   = kq * (HD / KSPL);

    float4 acc0 = make_float4(0,0,0,0);
    float4 acc1 = make_float4(0,0,0,0);
    float4 acc2 = make_float4(0,0,0,0);

#pragma unroll 1
    for (int kb = 0; kb < HD / KSPL; kb += KB) {
        const int kk = k0 + kb;
        float4 wav[KB], wbv[KB], wrv[KB];
#pragma unroll
        for (int j = 0; j < KB; ++j) {
            const size_t o = (size_t)(kk + j) * HD + colg;
            wav[j] = *(const float4*)(Wa + o);
            wbv[j] = *(const float4*)(Wb + o);
            wrv[j] = *(const float4*)(Wr + o);
        }
        float hreg[KB];
#pragma unroll
        for (int j = 0; j < KB; j += 4)
            *(float4*)&hreg[j] = *(const float4*)&g.hs[row][kk + j];
#pragma unroll
        for (int j = 0; j < KB; ++j) {
            const float h = hreg[j];
            fma4(acc0, h, wav[j]);
            fma4(acc1, h, wbv[j]);
            fma4(acc2, h, wrv[j]);
        }
    }

    if (kq != 0) {
        *(float4*)&g.pbuf[kq - 1][0][row][colg] = acc0;
        *(float4*)&g.pbuf[kq - 1][1][row][colg] = acc1;
        *(float4*)&g.pbuf[kq - 1][2][row][colg] = acc2;
    }
    __syncthreads();
    if (kq == 0) {
#pragma unroll
        for (int p = 0; p < KSPL - 1; ++p) {
            const float4 p0 = *(const float4*)&g.pbuf[p][0][row][colg];
            const float4 p1 = *(const float4*)&g.pbuf[p][1][row][colg];
            const float4 p2 = *(const float4*)&g.pbuf[p][2][row][colg];
            acc0.x += p0.x; acc0.y += p0.y; acc0.z += p0.z; acc0.w += p0.w;
            acc1.x += p1.x; acc1.y += p1.y; acc1.z += p1.z; acc1.w += p1.w;
            acc2.x += p2.x; acc2.y += p2.y; acc2.z += p2.z; acc2.w += p2.w;
        }
        const float4 bv = *(const float4*)(bias + colg);
        acc2.x += bv.x; acc2.y += bv.y; acc2.z += bv.z; acc2.w += bv.w;
        const size_t o = (size_t)(n0 + row) * HD + colg;
        *(float4*)(U + o) = acc0;
        *(float4*)(V + o) = acc1;
        *(float4*)(R + o) = acc2;
    }
}

// ---- G2: layer-1 gather (msgs on the fly from x, in_c=2) + layer-2 GEMMs ----
__global__ __launch_bounds__(NTHR) void g2k(
    const float* __restrict__ x, const int* __restrict__ ei,
    const float* __restrict__ attr,
    const float* __restrict__ lw1, const float* __restrict__ lb1,
    const float* __restrict__ root1, const float* __restrict__ bias1,
    const float* __restrict__ lw2, const float* __restrict__ lb2,
    const float* __restrict__ root2, const float* __restrict__ bias2,
    float* __restrict__ U2, float* __restrict__ V2, float* __restrict__ R2,
    int E)
{
    __shared__ Tile g;
    const int t = threadIdx.x;
    const int n0 = blockIdx.x * TR;

    // hs = x@root1 + bias1  (TR*HD == NTHR: one element per thread)
    for (int i = t; i < TR * HD; i += NTHR) {
        const int r = i >> 7, c = i & 127;
        const float x0 = x[(n0 + r) * 2 + 0], x1 = x[(n0 + r) * 2 + 1];
        g.hs[r][c] = fmaf(x0, root1[c], fmaf(x1, root1[HD + c], bias1[c]));
    }

    const int pad = scan_edges(ei, attr, E, n0, g, t);

    // gather layer-1 messages: msg[c] = a*(x@A1)[c] + (x@B1)[c]
    const int el = t >> 5;
    const int c4 = (t & 31) << 2;
    const float4 A0 = *(const float4*)(lw1 + c4);
    const float4 A1 = *(const float4*)(lw1 + HD + c4);
    const float4 B0 = *(const float4*)(lb1 + c4);
    const float4 B1 = *(const float4*)(lb1 + HD + c4);
#pragma unroll 2
    for (int base = 0; base < pad; base += 16) {
        const int   i = base + el;
        const int   r = g.lrow[i];
        const int   s = g.lsrc[i];
        const float a = g.lattr[i];
        const float2 xv = *(const float2*)(x + (size_t)s * 2);
        atomicAdd(&g.hs[r][c4 + 0], fmaf(a, fmaf(xv.x, A0.x, xv.y * A1.x), fmaf(xv.x, B0.x, xv.y * B1.x)));
        atomicAdd(&g.hs[r][c4 + 1], fmaf(a, fmaf(xv.x, A0.y, xv.y * A1.y), fmaf(xv.x, B0.y, xv.y * B1.y)));
        atomicAdd(&g.hs[r][c4 + 2], fmaf(a, fmaf(xv.x, A0.z, xv.y * A1.z), fmaf(xv.x, B0.z, xv.y * B1.z)));
        atomicAdd(&g.hs[r][c4 + 3], fmaf(a, fmaf(xv.x, A0.w, xv.y * A1.w), fmaf(xv.x, B0.w, xv.y * B1.w)));
    }
    __syncthreads();

    relu_hs(g, t);
    gemm3(g, n0, t, lw2, lb2, root2, bias2, U2, V2, R2);
}

// ---- G3: layer-2 gather + layer-3 GEMMs ----
__global__ __launch_bounds__(NTHR) void g3k(
    const int* __restrict__ ei, const float* __restrict__ attr,
    const float* __restrict__ U2, const float* __restrict__ V2,
    const float* __restrict__ R2,
    const float* __restrict__ lw3, const float* __restrict__ lb3,
    const float* __restrict__ root3, const float* __restrict__ bias3,
    float* __restrict__ U3, float* __restrict__ V3, float* __restrict__ R3,
    int E)
{
    __shared__ Tile g;
    const int t = threadIdx.x;
    const int n0 = blockIdx.x * TR;

    for (int i = t; i < TR * HD / 4; i += NTHR)
        ((float4*)&g.hs[0][0])[i] = ((const float4*)(R2 + (size_t)n0 * HD))[i];

    const int pad = scan_edges(ei, attr, E, n0, g, t);
    gather_uv(U2, V2, g, pad, t);
    relu_hs(g, t);
    gemm3(g, n0, t, lw3, lb3, root3, bias3, U3, V3, R3);
}

// ---- G4: layer-3 gather -> out (no relu, plain float4 stores) ----
__global__ __launch_bounds__(NTHR) void g4k(
    const int* __restrict__ ei, const float* __restrict__ attr,
    const float* __restrict__ U3, const float* __restrict__ V3,
    const float* __restrict__ R3, float* __restrict__ out, int E)
{
    __shared__ Tile g;
    const int t = threadIdx.x;
    const int n0 = blockIdx.x * TR;

    for (int i = t; i < TR * HD / 4; i += NTHR)
        ((float4*)&g.hs[0][0])[i] = ((const float4*)(R3 + (size_t)n0 * HD))[i];

    const int pad = scan_edges(ei, attr, E, n0, g, t);
    gather_uv(U3, V3, g, pad, t);

    for (int i = t; i < TR * HD / 4; i += NTHR)
        ((float4*)(out + (size_t)n0 * HD))[i] = ((const float4*)&g.hs[0][0])[i];
}

extern "C" void kernel_launch(void* const* d_in, const int* in_sizes, int n_in,
                              void* d_out, int out_size, void* d_ws, size_t ws_size,
                              hipStream_t stream) {
    const float* x     = (const float*)d_in[0];
    const int*   ei    = (const int*)  d_in[1];
    const float* attr  = (const float*)d_in[2];
    const float* lw1   = (const float*)d_in[3];
    const float* lb1   = (const float*)d_in[4];
    const float* root1 = (const float*)d_in[5];
    const float* bias1 = (const float*)d_in[6];
    const float* lw2   = (const float*)d_in[7];
    const float* lb2   = (const float*)d_in[8];
    const float* root2 = (const float*)d_in[9];
    const float* bias2 = (const float*)d_in[10];
    const float* lw3   = (const float*)d_in[11];
    const float* lb3   = (const float*)d_in[12];
    const float* root3 = (const float*)d_in[13];
    const float* bias3 = (const float*)d_in[14];

    const int N = in_sizes[0] / 2;   // x: [N,2]
    const int E = in_sizes[1] / 2;   // edge_index: [2,E]

    float* out = (float*)d_out;
    float* ws  = (float*)d_ws;
    float* U2 = ws + 0 * (size_t)N * HD;
    float* V2 = ws + 1 * (size_t)N * HD;
    float* R2 = ws + 2 * (size_t)N * HD;
    float* U3 = ws + 3 * (size_t)N * HD;
    float* V3 = ws + 4 * (size_t)N * HD;
    float* R3 = ws + 5 * (size_t)N * HD;

    const int ntiles = N / TR;   // 256 blocks, 1 per CU
    g2k<<<ntiles, NTHR, 0, stream>>>(x, ei, attr, lw1, lb1, root1, bias1,
                                     lw2, lb2, root2, bias2, U2, V2, R2, E);
    g3k<<<ntiles, NTHR, 0, stream>>>(ei, attr, U2, V2, R2,
                                     lw3, lb3, root3, bias3, U3, V3, R3, E);
    g4k<<<ntiles, NTHR, 0, stream>>>(ei, attr, U3, V3, R3, out, E);
}